// Round 2
// baseline (143.271 us; speedup 1.0000x reference)
//
#include <hip/hip_runtime.h>
#include <stdint.h>

// ---------------------------------------------------------------------------
// VCSMC step on MI355X. Bit-exact JAX threefry RNG under the
// jax_threefry_partitionable=True semantics (default since jax 0.4.36):
//   random_bits(key,32,shape)[i] = o0 ^ o1 of threefry2x32(key, (0, i))
//   split(key,n)[i]              = (o0, o1) of threefry2x32(key, (0, i))
// Heavy math collapsed via Q^2 = -Q  =>  expm(b*Q) = I + (1-e^-b) Q (exact).
// ---------------------------------------------------------------------------

#define TF_ROT(x0,x1,r) { x0 += x1; x1 = ((x1<<(r))|(x1>>(32-(r)))); x1 ^= x0; }

__host__ __device__ inline void tf2x32(uint32_t k0, uint32_t k1,
                                       uint32_t x0, uint32_t x1,
                                       uint32_t& o0, uint32_t& o1) {
  uint32_t ks2 = k0 ^ k1 ^ 0x1BD11BDAu;
  x0 += k0; x1 += k1;
  TF_ROT(x0,x1,13) TF_ROT(x0,x1,15) TF_ROT(x0,x1,26) TF_ROT(x0,x1,6)
  x0 += k1; x1 += ks2 + 1u;
  TF_ROT(x0,x1,17) TF_ROT(x0,x1,29) TF_ROT(x0,x1,16) TF_ROT(x0,x1,24)
  x0 += ks2; x1 += k0 + 2u;
  TF_ROT(x0,x1,13) TF_ROT(x0,x1,15) TF_ROT(x0,x1,26) TF_ROT(x0,x1,6)
  x0 += k0; x1 += k1 + 3u;
  TF_ROT(x0,x1,17) TF_ROT(x0,x1,29) TF_ROT(x0,x1,16) TF_ROT(x0,x1,24)
  x0 += k1; x1 += ks2 + 4u;
  TF_ROT(x0,x1,13) TF_ROT(x0,x1,15) TF_ROT(x0,x1,26) TF_ROT(x0,x1,6)
  x0 += ks2; x1 += k0 + 5u;
  o0 = x0; o1 = x1;
}

struct Keys {
  uint32_t kres0, kres1;   // categorical key
  uint32_t k2i0, k2i1;     // randint(i): lower-bits key (multiplier==0 for span 16)
  uint32_t k1o0, k1o1;     // randint(off): higher-bits key
  uint32_t k2o0, k2o1;     // randint(off): lower-bits key
  uint32_t ku10, ku11;     // uniform branch1
  uint32_t ku20, ku21;     // uniform branch2
};

// Partitionable random_bits: element i -> o0^o1 of counter (0, i).
__device__ inline uint32_t rb_fold(uint32_t k0, uint32_t k1, uint32_t i) {
  uint32_t o0, o1;
  tf2x32(k0, k1, 0u, i, o0, o1);
  return o0 ^ o1;
}

__device__ inline float u01f(uint32_t b) {
  return __uint_as_float((b >> 9) | 0x3F800000u) - 1.0f;
}

#define TINYF 1.17549435e-38f

// ---------------------------------------------------------------------------
// Kernel: site logits  sl[s][a] = site[s,:] @ W_site[:,a]   (S=1024, C=16, A=4)
// ---------------------------------------------------------------------------
__global__ __launch_bounds__(256) void k_site(const float* __restrict__ site,
                                              const float* __restrict__ Wsite,
                                              float* __restrict__ slw) {
  int s = blockIdx.x * 256 + threadIdx.x;  // 0..1023
  float a0 = 0.f, a1 = 0.f, a2 = 0.f, a3 = 0.f;
#pragma unroll
  for (int c = 0; c < 16; c++) {
    float sc = site[s * 16 + c];
    a0 += sc * Wsite[c * 4 + 0];
    a1 += sc * Wsite[c * 4 + 1];
    a2 += sc * Wsite[c * 4 + 2];
    a3 += sc * Wsite[c * 4 + 3];
  }
  float4 v; v.x = a0; v.y = a1; v.z = a2; v.w = a3;
  ((float4*)slw)[s] = v;
}

// ---------------------------------------------------------------------------
// Kernel: per-particle RNG + resampling + scalars + node logits
// block k (256 blocks x 256 threads)
// ---------------------------------------------------------------------------
__global__ __launch_bounds__(256) void k_setup(
    const float* __restrict__ logw, const float* __restrict__ b1r,
    const float* __restrict__ b2r, const int* __restrict__ lc,
    const float* __restrict__ emb, const float* __restrict__ logpi,
    const float* __restrict__ Wstat, const float* __restrict__ ldf,
    float* __restrict__ nlw, float* __restrict__ w1w, float* __restrict__ w2w,
    float* __restrict__ cw, int* __restrict__ pw, int* __restrict__ i1w,
    int* __restrict__ i2w, Keys kk) {
  int k = blockIdx.x, tid = threadIdx.x;
  __shared__ float sval[256];
  __shared__ int   sidx[256];
  __shared__ int   sh_i1, sh_i2;

  // --- categorical: gumbel(256x256) row k, argmax (first max wins) ---
  {
    uint32_t idx = (uint32_t)(k * 256 + tid);
    uint32_t b = rb_fold(kk.kres0, kk.kres1, idx);
    float u = fmaxf(TINYF, u01f(b) + TINYF);   // uniform(tiny, 1.0): (1-tiny)==1.0f
    float g = -logf(-logf(u));
    sval[tid] = g + logw[tid];
    sidx[tid] = tid;
  }
  __syncthreads();
  for (int st = 128; st > 0; st >>= 1) {
    if (tid < st) {
      float va = sval[tid], vb = sval[tid + st];
      int ia = sidx[tid], ib = sidx[tid + st];
      if (vb > va || (vb == va && ib < ia)) { sval[tid] = vb; sidx[tid] = ib; }
    }
    __syncthreads();
  }
  int p = sidx[0];

  if (tid == 0) {
    // randint(ki,(K,),0,16): span=16 -> multiplier=0 -> i = lower_bits % 16
    uint32_t i = rb_fold(kk.k2i0, kk.k2i1, (uint32_t)k) & 15u;
    // randint(koff,(K,),1,16): span=15, multiplier = (2^16 % 15)^2 % 15 = 1
    uint32_t h = rb_fold(kk.k1o0, kk.k1o1, (uint32_t)k) % 15u;
    uint32_t l = rb_fold(kk.k2o0, kk.k2o1, (uint32_t)k) % 15u;
    uint32_t off = 1u + (h + l) % 15u;
    uint32_t j = (i + off) & 15u;
    int i1 = (int)(i < j ? i : j);
    int i2 = (int)(i < j ? j : i);
    sh_i1 = i1; sh_i2 = i2;

    const float SUBR = 1.0f - 1e-6f;
    float u1 = fmaxf(1e-6f, u01f(rb_fold(kk.ku10, kk.ku11, (uint32_t)k)) * SUBR + 1e-6f);
    float u2 = fmaxf(1e-6f, u01f(rb_fold(kk.ku20, kk.ku21, (uint32_t)k)) * SUBR + 1e-6f);
    float b1 = -0.1f * logf(u1);
    float b2 = -0.1f * logf(u2);
    w1w[k] = 1.0f - expf(-b1);
    w2w[k] = 1.0f - expf(-b2);
    i1w[k] = i1; i2w[k] = i2; pw[k] = p;

    // prior over branch lengths (r+1 = 17 each)
    float sb = b1 + b2;
    for (int r = 0; r < 16; r++) sb += b1r[p * 16 + r] + b2r[p * 16 + r];
    float prior = -sb / 0.1f - 34.0f * logf(0.1f);

    // leaf counts -> topo prior + log_v_minus
    float topo_sum = 0.0f; int cnt = 0;
    for (int t = 0; t < 15; t++) {
      int lct;
      if (t == i1)      lct = lc[p * 16 + i1] + lc[p * 16 + i2];
      else if (t == i2) lct = lc[p * 16 + 15];
      else              lct = lc[p * 16 + t];
      int ti = 2 * lct - 3; ti = ti < 0 ? 0 : (ti > 63 ? 63 : ti);
      if (lct >= 2) topo_sum -= ldf[ti];
      if (lct > 1) cnt++;
    }
    float log_v_minus = logf(fmaxf((float)cnt, 1.0f));
    float log_v_plus = logf(120.0f);  // log(16*15/2)
    cw[k] = prior + topo_sum - logpi[p] + log_v_minus - log_v_plus;
  }
  __syncthreads();

  // node logits nl[t][a] = emb_new[t,:] @ W_stat[:,a], t in [0,15)
  if (tid < 60) {
    int t = tid >> 2, a = tid & 3;
    int i1 = sh_i1, i2 = sh_i2;
    int p2 = sidx[0];
    float acc = 0.0f;
    if (t == i1) {
      const float* e1 = emb + ((size_t)p2 * 16 + i1) * 64;
      const float* e2 = emb + ((size_t)p2 * 16 + i2) * 64;
      for (int d = 0; d < 64; d++) acc += 0.5f * (e1[d] + e2[d]) * Wstat[d * 4 + a];
    } else {
      int src = (t == i2) ? 15 : t;
      const float* e = emb + ((size_t)p2 * 16 + src) * 64;
      for (int d = 0; d < 64; d++) acc += e[d] * Wstat[d * 4 + a];
    }
    nlw[k * 60 + t * 4 + a] = acc;
  }
}

// ---------------------------------------------------------------------------
// Main kernel: grid (4, 256) x 256 threads; thread handles one (k, s).
//  - merged-node stat -> new_logf (analytic expm: P = I + (1-e^-b) Q)
//  - per slot t: sum_s [ lse(logf_src + logits) - lse(logits) ]
//  - deterministic block partials Lpart[k][bx][t]
// ---------------------------------------------------------------------------
__global__ __launch_bounds__(256) void k_main(
    const float* __restrict__ lfg, const float* __restrict__ slw,
    const float* __restrict__ nlw, const float* __restrict__ w1w,
    const float* __restrict__ w2w, const int* __restrict__ pw,
    const int* __restrict__ i1w, const int* __restrict__ i2w,
    float* __restrict__ Lpart) {
  int k = blockIdx.y, bx = blockIdx.x, tid = threadIdx.x;
  int s = bx * 256 + tid;
  __shared__ float snl[60];
  __shared__ float sred[15 * 4];
  if (tid < 60) snl[tid] = nlw[k * 60 + tid];
  __syncthreads();
  int p = pw[k], i1 = i1w[k], i2 = i2w[k];
  float w1 = w1w[k], w2 = w2w[k];
  const float4 sl = ((const float4*)slw)[s];
  const float* base = lfg + (size_t)p * 16 * 1024 * 4;

  // merged-node stationary probs (softmax of nl[i1] + sl)
  float q0 = snl[i1 * 4 + 0] + sl.x, q1 = snl[i1 * 4 + 1] + sl.y;
  float q2 = snl[i1 * 4 + 2] + sl.z, q3 = snl[i1 * 4 + 3] + sl.w;
  float qm = fmaxf(fmaxf(q0, q1), fmaxf(q2, q3));
  float e0 = expf(q0 - qm), e1 = expf(q1 - qm), e2 = expf(q2 - qm), e3 = expf(q3 - qm);
  float inv = 1.0f / (e0 + e1 + e2 + e3);
  float st0 = e0 * inv, st1 = e1 * inv, st2 = e2 * inv, st3 = e3 * inv;

  float4 lf1 = *(const float4*)(base + ((size_t)i1 * 1024 + s) * 4);
  float4 lf2 = *(const float4*)(base + ((size_t)i2 * 1024 + s) * 4);
  float f10 = expf(lf1.x), f11 = expf(lf1.y), f12 = expf(lf1.z), f13 = expf(lf1.w);
  float f20 = expf(lf2.x), f21 = expf(lf2.y), f22 = expf(lf2.z), f23 = expf(lf2.w);
  float dot1 = st0 * f10 + st1 * f11 + st2 * f12 + st3 * f13;
  float dot2 = st0 * f20 + st1 * f21 + st2 * f22 + st3 * f23;
  float om1 = 1.0f - w1, om2 = 1.0f - w2;
  // P = I + (1 - e^-b) Q  =>  (P f)[a] = (1-w) f[a] + w * <stat, f>
  float n0 = logf(om1 * f10 + w1 * dot1 + 1e-30f) + logf(om2 * f20 + w2 * dot2 + 1e-30f);
  float n1 = logf(om1 * f11 + w1 * dot1 + 1e-30f) + logf(om2 * f21 + w2 * dot2 + 1e-30f);
  float n2 = logf(om1 * f12 + w1 * dot1 + 1e-30f) + logf(om2 * f22 + w2 * dot2 + 1e-30f);
  float n3 = logf(om1 * f13 + w1 * dot1 + 1e-30f) + logf(om2 * f23 + w2 * dot2 + 1e-30f);

#pragma unroll
  for (int t = 0; t < 15; t++) {
    float l0 = snl[t * 4 + 0] + sl.x, l1 = snl[t * 4 + 1] + sl.y;
    float l2 = snl[t * 4 + 2] + sl.z, l3 = snl[t * 4 + 3] + sl.w;
    float lm = fmaxf(fmaxf(l0, l1), fmaxf(l2, l3));
    float lse_l = lm + logf(expf(l0 - lm) + expf(l1 - lm) + expf(l2 - lm) + expf(l3 - lm));
    float x0, x1, x2, x3;
    if (t == i1) { x0 = n0; x1 = n1; x2 = n2; x3 = n3; }
    else {
      int srct = (t == i2) ? 15 : t;
      float4 lf = *(const float4*)(base + ((size_t)srct * 1024 + s) * 4);
      x0 = lf.x; x1 = lf.y; x2 = lf.z; x3 = lf.w;
    }
    x0 += l0; x1 += l1; x2 += l2; x3 += l3;
    float xm = fmaxf(fmaxf(x0, x1), fmaxf(x2, x3));
    float contr = xm + logf(expf(x0 - xm) + expf(x1 - xm) + expf(x2 - xm) + expf(x3 - xm)) - lse_l;
    // wave (64) reduce, then per-wave partial to LDS
    float v = contr;
    for (int o = 32; o > 0; o >>= 1) v += __shfl_down(v, o, 64);
    if ((tid & 63) == 0) sred[t * 4 + (tid >> 6)] = v;
  }
  __syncthreads();
  if (tid < 15) {
    float sum = sred[tid * 4 + 0] + sred[tid * 4 + 1] + sred[tid * 4 + 2] + sred[tid * 4 + 3];
    Lpart[(size_t)k * 60 + bx * 15 + tid] = sum;
  }
}

// ---------------------------------------------------------------------------
__global__ __launch_bounds__(256) void k_final(const float* __restrict__ cw,
                                               const float* __restrict__ Lpart,
                                               float* __restrict__ out) {
  int k = threadIdx.x;
  float sum = cw[k];
  for (int q = 0; q < 60; q++) sum += Lpart[k * 60 + q];
  out[k] = sum;
}

// ---------------------------------------------------------------------------
extern "C" void kernel_launch(void* const* d_in, const int* in_sizes, int n_in,
                              void* d_out, int out_size, void* d_ws, size_t ws_size,
                              hipStream_t stream) {
  const float* logw  = (const float*)d_in[0];
  const float* b1r   = (const float*)d_in[1];
  const float* b2r   = (const float*)d_in[2];
  const int*   lc    = (const int*)d_in[3];
  const float* emb   = (const float*)d_in[4];
  const float* lfg   = (const float*)d_in[5];
  const float* logpi = (const float*)d_in[6];
  const float* site  = (const float*)d_in[7];
  const float* Wstat = (const float*)d_in[8];
  const float* Wsite = (const float*)d_in[9];
  const float* ldf   = (const float*)d_in[10];

  char* w = (char*)d_ws;
  float* slw   = (float*)w; w += 1024 * 4 * 4;
  float* nlw   = (float*)w; w += 256 * 60 * 4;
  float* w1w   = (float*)w; w += 256 * 4;
  float* w2w   = (float*)w; w += 256 * 4;
  float* cw    = (float*)w; w += 256 * 4;
  int*   pw    = (int*)w;   w += 256 * 4;
  int*   i1w   = (int*)w;   w += 256 * 4;
  int*   i2w   = (int*)w;   w += 256 * 4;
  float* Lpart = (float*)w; w += 256 * 60 * 4;

  // Host-side subkey derivation under jax_threefry_partitionable=True:
  // split(key, n)[i] = (o0, o1) of threefry2x32(key, counter=(0, i)).
  // key(42) = (0, 42).
  uint32_t S0[5], S1[5];
  for (uint32_t i = 0; i < 5; i++) tf2x32(0u, 42u, 0u, i, S0[i], S1[i]);
  // order: kres, ki, koff, ku1, ku2
  Keys kk;
  kk.kres0 = S0[0]; kk.kres1 = S1[0];
  kk.ku10  = S0[3]; kk.ku11  = S1[3];
  kk.ku20  = S0[4]; kk.ku21  = S1[4];
  { // randint(ki): k1,k2 = split(ki,2) -> keys at counters (0,0) and (0,1)
    uint32_t a0, a1, b0, b1;
    tf2x32(S0[1], S1[1], 0u, 0u, a0, a1);  // k1 (higher bits) -- unused (span 16)
    tf2x32(S0[1], S1[1], 0u, 1u, b0, b1);  // k2 (lower bits)
    (void)a0; (void)a1;
    kk.k2i0 = b0; kk.k2i1 = b1;
  }
  { // randint(koff): k1,k2 = split(koff,2)
    uint32_t a0, a1, b0, b1;
    tf2x32(S0[2], S1[2], 0u, 0u, a0, a1);  // k1 (higher bits)
    tf2x32(S0[2], S1[2], 0u, 1u, b0, b1);  // k2 (lower bits)
    kk.k1o0 = a0; kk.k1o1 = a1;
    kk.k2o0 = b0; kk.k2o1 = b1;
  }

  k_site<<<4, 256, 0, stream>>>(site, Wsite, slw);
  k_setup<<<256, 256, 0, stream>>>(logw, b1r, b2r, lc, emb, logpi, Wstat, ldf,
                                   nlw, w1w, w2w, cw, pw, i1w, i2w, kk);
  dim3 g(4, 256);
  k_main<<<g, 256, 0, stream>>>(lfg, slw, nlw, w1w, w2w, pw, i1w, i2w, Lpart);
  k_final<<<1, 256, 0, stream>>>(cw, Lpart, (float*)d_out);
}

// Round 3
// 134.080 us; speedup vs baseline: 1.0686x; 1.0686x over previous
//
#include <hip/hip_runtime.h>
#include <stdint.h>

// ---------------------------------------------------------------------------
// VCSMC step on MI355X. Bit-exact JAX threefry RNG (partitionable semantics).
// R3: fast transcendentals (__expf/__logf) everywhere except discrete-RNG
// paths; slot-likelihood factored as Lorig[p][slot] (coalesced single pass
// over log_felsensteins) + per-k merged-node term.
//   expm collapse: Q^2 = -Q  =>  expm(b*Q) = I + (1-e^-b) Q (exact).
//   lse trick: precompute exp(site_logits), exp(node_logits) -> logits-lse
//   is a dot product; only exp(logf) + 2 logs per lse pair remain.
// ---------------------------------------------------------------------------

#define TF_ROT(x0,x1,r) { x0 += x1; x1 = ((x1<<(r))|(x1>>(32-(r)))); x1 ^= x0; }

__host__ __device__ inline void tf2x32(uint32_t k0, uint32_t k1,
                                       uint32_t x0, uint32_t x1,
                                       uint32_t& o0, uint32_t& o1) {
  uint32_t ks2 = k0 ^ k1 ^ 0x1BD11BDAu;
  x0 += k0; x1 += k1;
  TF_ROT(x0,x1,13) TF_ROT(x0,x1,15) TF_ROT(x0,x1,26) TF_ROT(x0,x1,6)
  x0 += k1; x1 += ks2 + 1u;
  TF_ROT(x0,x1,17) TF_ROT(x0,x1,29) TF_ROT(x0,x1,16) TF_ROT(x0,x1,24)
  x0 += ks2; x1 += k0 + 2u;
  TF_ROT(x0,x1,13) TF_ROT(x0,x1,15) TF_ROT(x0,x1,26) TF_ROT(x0,x1,6)
  x0 += k0; x1 += k1 + 3u;
  TF_ROT(x0,x1,17) TF_ROT(x0,x1,29) TF_ROT(x0,x1,16) TF_ROT(x0,x1,24)
  x0 += k1; x1 += ks2 + 4u;
  TF_ROT(x0,x1,13) TF_ROT(x0,x1,15) TF_ROT(x0,x1,26) TF_ROT(x0,x1,6)
  x0 += ks2; x1 += k0 + 5u;
  o0 = x0; o1 = x1;
}

struct Keys {
  uint32_t kres0, kres1;
  uint32_t k2i0, k2i1;
  uint32_t k1o0, k1o1;
  uint32_t k2o0, k2o1;
  uint32_t ku10, ku11;
  uint32_t ku20, ku21;
};

// Partitionable random_bits: element i -> o0^o1 of counter (0, i).
__device__ inline uint32_t rb_fold(uint32_t k0, uint32_t k1, uint32_t i) {
  uint32_t o0, o1;
  tf2x32(k0, k1, 0u, i, o0, o1);
  return o0 ^ o1;
}

__device__ inline float u01f(uint32_t b) {
  return __uint_as_float((b >> 9) | 0x3F800000u) - 1.0f;
}

#define TINYF 1.17549435e-38f

// ---------------------------------------------------------------------------
// Kernel A: esl[s][a] = exp(site[s,:] @ W_site[:,a])   (S=1024, C=16, A=4)
// ---------------------------------------------------------------------------
__global__ __launch_bounds__(256) void k_esl(const float* __restrict__ site,
                                             const float* __restrict__ Wsite,
                                             float* __restrict__ eslw) {
  int s = blockIdx.x * 256 + threadIdx.x;
  float a0 = 0.f, a1 = 0.f, a2 = 0.f, a3 = 0.f;
#pragma unroll
  for (int c = 0; c < 16; c++) {
    float sc = site[s * 16 + c];
    a0 += sc * Wsite[c * 4 + 0];
    a1 += sc * Wsite[c * 4 + 1];
    a2 += sc * Wsite[c * 4 + 2];
    a3 += sc * Wsite[c * 4 + 3];
  }
  float4 v; v.x = __expf(a0); v.y = __expf(a1); v.z = __expf(a2); v.w = __expf(a3);
  ((float4*)eslw)[s] = v;
}

// ---------------------------------------------------------------------------
// Kernel B: per-particle RNG + resampling + scalar constant + merged-node
// exp-logits. Precise logf kept for discrete RNG (argmax tie safety).
// ---------------------------------------------------------------------------
__global__ __launch_bounds__(256) void k_setup(
    const float* __restrict__ logw, const float* __restrict__ b1r,
    const float* __restrict__ b2r, const int* __restrict__ lc,
    const float* __restrict__ emb, const float* __restrict__ logpi,
    const float* __restrict__ Wstat, const float* __restrict__ ldf,
    float* __restrict__ enlm, float* __restrict__ w1w, float* __restrict__ w2w,
    float* __restrict__ cw, int* __restrict__ pw, int* __restrict__ i1w,
    int* __restrict__ i2w, Keys kk) {
  int k = blockIdx.x, tid = threadIdx.x;
  __shared__ float sval[256];
  __shared__ int   sidx[256];
  __shared__ int   sh_i1, sh_i2;

  // --- categorical: gumbel row k, argmax (first max wins) ---
  {
    uint32_t b = rb_fold(kk.kres0, kk.kres1, (uint32_t)(k * 256 + tid));
    float u = fmaxf(TINYF, u01f(b) + TINYF);
    float g = -logf(-logf(u));            // precise: discrete decision
    sval[tid] = g + logw[tid];
    sidx[tid] = tid;
  }
  __syncthreads();
  for (int st = 128; st > 0; st >>= 1) {
    if (tid < st) {
      float va = sval[tid], vb = sval[tid + st];
      int ia = sidx[tid], ib = sidx[tid + st];
      if (vb > va || (vb == va && ib < ia)) { sval[tid] = vb; sidx[tid] = ib; }
    }
    __syncthreads();
  }
  int p = sidx[0];

  if (tid == 0) {
    // randint(ki,(K,),0,16): span=16 -> lower_bits % 16
    uint32_t i = rb_fold(kk.k2i0, kk.k2i1, (uint32_t)k) & 15u;
    // randint(koff,(K,),1,16): span=15, multiplier = 1
    uint32_t h = rb_fold(kk.k1o0, kk.k1o1, (uint32_t)k) % 15u;
    uint32_t l = rb_fold(kk.k2o0, kk.k2o1, (uint32_t)k) % 15u;
    uint32_t off = 1u + (h + l) % 15u;
    uint32_t j = (i + off) & 15u;
    int i1 = (int)(i < j ? i : j);
    int i2 = (int)(i < j ? j : i);
    sh_i1 = i1; sh_i2 = i2;

    const float SUBR = 1.0f - 1e-6f;
    float u1 = fmaxf(1e-6f, u01f(rb_fold(kk.ku10, kk.ku11, (uint32_t)k)) * SUBR + 1e-6f);
    float u2 = fmaxf(1e-6f, u01f(rb_fold(kk.ku20, kk.ku21, (uint32_t)k)) * SUBR + 1e-6f);
    float b1 = -0.1f * logf(u1);          // precise: matches ref branch length
    float b2 = -0.1f * logf(u2);
    w1w[k] = 1.0f - expf(-b1);
    w2w[k] = 1.0f - expf(-b2);
    i1w[k] = i1; i2w[k] = i2; pw[k] = p;

    float sb = b1 + b2;
    for (int r = 0; r < 16; r++) sb += b1r[p * 16 + r] + b2r[p * 16 + r];
    float prior = -sb / 0.1f - 34.0f * logf(0.1f);

    float topo_sum = 0.0f; int cnt = 0;
    for (int t = 0; t < 15; t++) {
      int lct;
      if (t == i1)      lct = lc[p * 16 + i1] + lc[p * 16 + i2];
      else if (t == i2) lct = lc[p * 16 + 15];
      else              lct = lc[p * 16 + t];
      int ti = 2 * lct - 3; ti = ti < 0 ? 0 : (ti > 63 ? 63 : ti);
      if (lct >= 2) topo_sum -= ldf[ti];
      if (lct > 1) cnt++;
    }
    float log_v_minus = logf(fmaxf((float)cnt, 1.0f));
    float log_v_plus = logf(120.0f);
    cw[k] = prior + topo_sum - logpi[p] + log_v_minus - log_v_plus;
  }
  __syncthreads();

  // merged-node exp-logits enlm[k][a] = exp(0.5*(e_i1+e_i2) @ Wstat[:,a])
  if (tid < 4) {
    int a = tid, i1 = sh_i1, i2 = sh_i2, p2 = sidx[0];
    const float* e1 = emb + ((size_t)p2 * 16 + i1) * 64;
    const float* e2 = emb + ((size_t)p2 * 16 + i2) * 64;
    float acc = 0.0f;
    for (int d = 0; d < 64; d++) acc += 0.5f * (e1[d] + e2[d]) * Wstat[d * 4 + a];
    enlm[k * 4 + a] = __expf(acc);
  }
}

// ---------------------------------------------------------------------------
// Kernel C: Lorig partials. Grid (4 sblk, 256 p) x 256 threads.
// Lorig[p][t] = sum_s [ log(sum_a exp(logf)*enl*esl) - log(sum_a enl*esl) ]
// Coalesced single pass over log_felsensteins.
// ---------------------------------------------------------------------------
__global__ __launch_bounds__(256) void k_lorig(
    const float* __restrict__ lfg, const float* __restrict__ eslw,
    const float* __restrict__ emb, const float* __restrict__ Wstat,
    float* __restrict__ Lpart) {
  int p = blockIdx.y, sblk = blockIdx.x, tid = threadIdx.x;
  __shared__ float enl[64];
  __shared__ float sred[16 * 4];
  if (tid < 64) {
    int t = tid >> 2, a = tid & 3;
    const float* e = emb + ((size_t)p * 16 + t) * 64;
    float acc = 0.0f;
    for (int d = 0; d < 64; d++) acc += e[d] * Wstat[d * 4 + a];
    enl[tid] = __expf(acc);
  }
  __syncthreads();
  int s = sblk * 256 + tid;
  const float4 esl = ((const float4*)eslw)[s];
  const float* base = lfg + (size_t)p * 65536;  // 16 slots * 1024 sites * 4

  float acc[16];
#pragma unroll
  for (int t = 0; t < 16; t++) {
    float4 lf = *(const float4*)(base + t * 4096 + s * 4);
    float w0 = enl[t * 4 + 0] * esl.x, w1 = enl[t * 4 + 1] * esl.y;
    float w2 = enl[t * 4 + 2] * esl.z, w3 = enl[t * 4 + 3] * esl.w;
    float S1 = w0 + w1 + w2 + w3;
    float S2 = __expf(lf.x) * w0 + __expf(lf.y) * w1 +
               __expf(lf.z) * w2 + __expf(lf.w) * w3;
    acc[t] = __logf(S2) - __logf(S1);
  }
#pragma unroll
  for (int t = 0; t < 16; t++) {
    float v = acc[t];
    for (int o = 32; o > 0; o >>= 1) v += __shfl_down(v, o, 64);
    if ((tid & 63) == 0) sred[t * 4 + (tid >> 6)] = v;
  }
  __syncthreads();
  if (tid < 16) {
    float s4 = sred[tid * 4 + 0] + sred[tid * 4 + 1] + sred[tid * 4 + 2] + sred[tid * 4 + 3];
    Lpart[((size_t)p * 4 + sblk) * 16 + tid] = s4;
  }
}

// ---------------------------------------------------------------------------
// Kernel D: merged-node term over sites + final combine. 256 blocks (k) x 1024.
// ---------------------------------------------------------------------------
__global__ __launch_bounds__(1024) void k_fin(
    const float* __restrict__ lfg, const float* __restrict__ eslw,
    const float* __restrict__ enlm, const float* __restrict__ w1w,
    const float* __restrict__ w2w, const int* __restrict__ pw,
    const int* __restrict__ i1w, const int* __restrict__ i2w,
    const float* __restrict__ cw, const float* __restrict__ Lpart,
    float* __restrict__ out) {
  int k = blockIdx.x, tid = threadIdx.x;
  __shared__ float sred[16];
  int p = pw[k], i1 = i1w[k], i2 = i2w[k];
  float w1 = w1w[k], w2 = w2w[k];
  float om1 = 1.0f - w1, om2 = 1.0f - w2;
  float m0 = enlm[k * 4 + 0], m1 = enlm[k * 4 + 1];
  float m2 = enlm[k * 4 + 2], m3 = enlm[k * 4 + 3];
  const float* base = lfg + (size_t)p * 65536;

  int s = tid;
  const float4 esl = ((const float4*)eslw)[s];
  float t0 = m0 * esl.x, t1 = m1 * esl.y, t2 = m2 * esl.z, t3 = m3 * esl.w;
  float T = t0 + t1 + t2 + t3;
  float invT = 1.0f / T;
  float4 lf1 = *(const float4*)(base + i1 * 4096 + s * 4);
  float4 lf2 = *(const float4*)(base + i2 * 4096 + s * 4);
  float f10 = __expf(lf1.x), f11 = __expf(lf1.y), f12 = __expf(lf1.z), f13 = __expf(lf1.w);
  float f20 = __expf(lf2.x), f21 = __expf(lf2.y), f22 = __expf(lf2.z), f23 = __expf(lf2.w);
  float dot1 = (t0 * f10 + t1 * f11 + t2 * f12 + t3 * f13) * invT;
  float dot2 = (t0 * f20 + t1 * f21 + t2 * f22 + t3 * f23) * invT;
  // P = I + (1-e^-b) Q: (P f)[a] = (1-w) f[a] + w * <stat,f>
  float n0 = __logf(om1 * f10 + w1 * dot1 + 1e-30f) + __logf(om2 * f20 + w2 * dot2 + 1e-30f);
  float n1 = __logf(om1 * f11 + w1 * dot1 + 1e-30f) + __logf(om2 * f21 + w2 * dot2 + 1e-30f);
  float n2 = __logf(om1 * f12 + w1 * dot1 + 1e-30f) + __logf(om2 * f22 + w2 * dot2 + 1e-30f);
  float n3 = __logf(om1 * f13 + w1 * dot1 + 1e-30f) + __logf(om2 * f23 + w2 * dot2 + 1e-30f);
  // lse(n + log(t)) - log(T)
  float S2 = __expf(n0) * t0 + __expf(n1) * t1 + __expf(n2) * t2 + __expf(n3) * t3;
  float tot = __logf(S2) - __logf(T);

  for (int o = 32; o > 0; o >>= 1) tot += __shfl_down(tot, o, 64);
  if ((tid & 63) == 0) sred[tid >> 6] = tot;
  __syncthreads();
  if (tid == 0) {
    float site_sum = 0.0f;
    for (int q = 0; q < 16; q++) site_sum += sred[q];
    const float* Lp = Lpart + (size_t)p * 64;
    float Ls = 0.0f;
    for (int q = 0; q < 64; q++) Ls += Lp[q];
    for (int sb = 0; sb < 4; sb++) Ls -= Lp[sb * 16 + i1] + Lp[sb * 16 + i2];
    out[k] = cw[k] + Ls + site_sum;
  }
}

// ---------------------------------------------------------------------------
extern "C" void kernel_launch(void* const* d_in, const int* in_sizes, int n_in,
                              void* d_out, int out_size, void* d_ws, size_t ws_size,
                              hipStream_t stream) {
  const float* logw  = (const float*)d_in[0];
  const float* b1r   = (const float*)d_in[1];
  const float* b2r   = (const float*)d_in[2];
  const int*   lc    = (const int*)d_in[3];
  const float* emb   = (const float*)d_in[4];
  const float* lfg   = (const float*)d_in[5];
  const float* logpi = (const float*)d_in[6];
  const float* site  = (const float*)d_in[7];
  const float* Wstat = (const float*)d_in[8];
  const float* Wsite = (const float*)d_in[9];
  const float* ldf   = (const float*)d_in[10];

  char* w = (char*)d_ws;
  float* eslw  = (float*)w; w += 1024 * 4 * 4;
  float* enlm  = (float*)w; w += 256 * 4 * 4;
  float* w1w   = (float*)w; w += 256 * 4;
  float* w2w   = (float*)w; w += 256 * 4;
  float* cw    = (float*)w; w += 256 * 4;
  int*   pw    = (int*)w;   w += 256 * 4;
  int*   i1w   = (int*)w;   w += 256 * 4;
  int*   i2w   = (int*)w;   w += 256 * 4;
  float* Lpart = (float*)w; w += 256 * 64 * 4;

  // Host-side subkeys, jax_threefry_partitionable=True semantics.
  uint32_t S0[5], S1[5];
  for (uint32_t i = 0; i < 5; i++) tf2x32(0u, 42u, 0u, i, S0[i], S1[i]);
  Keys kk;
  kk.kres0 = S0[0]; kk.kres1 = S1[0];
  kk.ku10  = S0[3]; kk.ku11  = S1[3];
  kk.ku20  = S0[4]; kk.ku21  = S1[4];
  {
    uint32_t a0, a1, b0, b1;
    tf2x32(S0[1], S1[1], 0u, 0u, a0, a1);
    tf2x32(S0[1], S1[1], 0u, 1u, b0, b1);
    (void)a0; (void)a1;
    kk.k2i0 = b0; kk.k2i1 = b1;
  }
  {
    uint32_t a0, a1, b0, b1;
    tf2x32(S0[2], S1[2], 0u, 0u, a0, a1);
    tf2x32(S0[2], S1[2], 0u, 1u, b0, b1);
    kk.k1o0 = a0; kk.k1o1 = a1;
    kk.k2o0 = b0; kk.k2o1 = b1;
  }

  k_esl<<<4, 256, 0, stream>>>(site, Wsite, eslw);
  k_setup<<<256, 256, 0, stream>>>(logw, b1r, b2r, lc, emb, logpi, Wstat, ldf,
                                   enlm, w1w, w2w, cw, pw, i1w, i2w, kk);
  dim3 gC(4, 256);
  k_lorig<<<gC, 256, 0, stream>>>(lfg, eslw, emb, Wstat, Lpart);
  k_fin<<<256, 1024, 0, stream>>>(lfg, eslw, enlm, w1w, w2w, pw, i1w, i2w,
                                  cw, Lpart, (float*)d_out);
}

// Round 4
// 129.050 us; speedup vs baseline: 1.1102x; 1.0390x over previous
//
#include <hip/hip_runtime.h>
#include <stdint.h>

// ---------------------------------------------------------------------------
// VCSMC step on MI355X. Bit-exact JAX threefry RNG (partitionable semantics).
// R4: early-exit k_lorig on particles never resampled (used[] flags, ~37%
// traffic cut), log2-domain accumulation, parallel k_fin tail.
//   expm collapse: Q^2 = -Q  =>  expm(b*Q) = I + (1-e^-b) Q (exact).
// ---------------------------------------------------------------------------

#define TF_ROT(x0,x1,r) { x0 += x1; x1 = ((x1<<(r))|(x1>>(32-(r)))); x1 ^= x0; }

__host__ __device__ inline void tf2x32(uint32_t k0, uint32_t k1,
                                       uint32_t x0, uint32_t x1,
                                       uint32_t& o0, uint32_t& o1) {
  uint32_t ks2 = k0 ^ k1 ^ 0x1BD11BDAu;
  x0 += k0; x1 += k1;
  TF_ROT(x0,x1,13) TF_ROT(x0,x1,15) TF_ROT(x0,x1,26) TF_ROT(x0,x1,6)
  x0 += k1; x1 += ks2 + 1u;
  TF_ROT(x0,x1,17) TF_ROT(x0,x1,29) TF_ROT(x0,x1,16) TF_ROT(x0,x1,24)
  x0 += ks2; x1 += k0 + 2u;
  TF_ROT(x0,x1,13) TF_ROT(x0,x1,15) TF_ROT(x0,x1,26) TF_ROT(x0,x1,6)
  x0 += k0; x1 += k1 + 3u;
  TF_ROT(x0,x1,17) TF_ROT(x0,x1,29) TF_ROT(x0,x1,16) TF_ROT(x0,x1,24)
  x0 += k1; x1 += ks2 + 4u;
  TF_ROT(x0,x1,13) TF_ROT(x0,x1,15) TF_ROT(x0,x1,26) TF_ROT(x0,x1,6)
  x0 += ks2; x1 += k0 + 5u;
  o0 = x0; o1 = x1;
}

struct Keys {
  uint32_t kres0, kres1;
  uint32_t k2i0, k2i1;
  uint32_t k1o0, k1o1;
  uint32_t k2o0, k2o1;
  uint32_t ku10, ku11;
  uint32_t ku20, ku21;
};

__device__ inline uint32_t rb_fold(uint32_t k0, uint32_t k1, uint32_t i) {
  uint32_t o0, o1;
  tf2x32(k0, k1, 0u, i, o0, o1);
  return o0 ^ o1;
}

__device__ inline float u01f(uint32_t b) {
  return __uint_as_float((b >> 9) | 0x3F800000u) - 1.0f;
}

#define TINYF 1.17549435e-38f

// ---------------------------------------------------------------------------
// Kernel A: esl[s][a] = exp(site logits); block 0 also zeroes used[].
// ---------------------------------------------------------------------------
__global__ __launch_bounds__(256) void k_pre(const float* __restrict__ site,
                                             const float* __restrict__ Wsite,
                                             float* __restrict__ eslw,
                                             int* __restrict__ used) {
  int tid = threadIdx.x;
  int s = blockIdx.x * 256 + tid;
  if (blockIdx.x == 0) used[tid] = 0;
  float a0 = 0.f, a1 = 0.f, a2 = 0.f, a3 = 0.f;
#pragma unroll
  for (int c = 0; c < 16; c++) {
    float sc = site[s * 16 + c];
    a0 += sc * Wsite[c * 4 + 0];
    a1 += sc * Wsite[c * 4 + 1];
    a2 += sc * Wsite[c * 4 + 2];
    a3 += sc * Wsite[c * 4 + 3];
  }
  float4 v; v.x = __expf(a0); v.y = __expf(a1); v.z = __expf(a2); v.w = __expf(a3);
  ((float4*)eslw)[s] = v;
}

// ---------------------------------------------------------------------------
// Kernel B: per-particle RNG + resampling + scalar constant + merged-node
// exp-logits + used-flag. Precise logf kept for discrete-RNG paths.
// ---------------------------------------------------------------------------
__global__ __launch_bounds__(256) void k_setup(
    const float* __restrict__ logw, const float* __restrict__ b1r,
    const float* __restrict__ b2r, const int* __restrict__ lc,
    const float* __restrict__ emb, const float* __restrict__ logpi,
    const float* __restrict__ Wstat, const float* __restrict__ ldf,
    float* __restrict__ enlm, float* __restrict__ w1w, float* __restrict__ w2w,
    float* __restrict__ cw, int* __restrict__ pw, int* __restrict__ i1w,
    int* __restrict__ i2w, int* __restrict__ used, Keys kk) {
  int k = blockIdx.x, tid = threadIdx.x;
  __shared__ float sval[256];
  __shared__ int   sidx[256];
  __shared__ int   sh_i1, sh_i2;

  {
    uint32_t b = rb_fold(kk.kres0, kk.kres1, (uint32_t)(k * 256 + tid));
    float u = fmaxf(TINYF, u01f(b) + TINYF);
    float g = -logf(-logf(u));            // precise: discrete decision
    sval[tid] = g + logw[tid];
    sidx[tid] = tid;
  }
  __syncthreads();
  for (int st = 128; st > 0; st >>= 1) {
    if (tid < st) {
      float va = sval[tid], vb = sval[tid + st];
      int ia = sidx[tid], ib = sidx[tid + st];
      if (vb > va || (vb == va && ib < ia)) { sval[tid] = vb; sidx[tid] = ib; }
    }
    __syncthreads();
  }
  int p = sidx[0];

  if (tid == 0) {
    used[p] = 1;                           // benign same-value race
    uint32_t i = rb_fold(kk.k2i0, kk.k2i1, (uint32_t)k) & 15u;
    uint32_t h = rb_fold(kk.k1o0, kk.k1o1, (uint32_t)k) % 15u;
    uint32_t l = rb_fold(kk.k2o0, kk.k2o1, (uint32_t)k) % 15u;
    uint32_t off = 1u + (h + l) % 15u;
    uint32_t j = (i + off) & 15u;
    int i1 = (int)(i < j ? i : j);
    int i2 = (int)(i < j ? j : i);
    sh_i1 = i1; sh_i2 = i2;

    const float SUBR = 1.0f - 1e-6f;
    float u1 = fmaxf(1e-6f, u01f(rb_fold(kk.ku10, kk.ku11, (uint32_t)k)) * SUBR + 1e-6f);
    float u2 = fmaxf(1e-6f, u01f(rb_fold(kk.ku20, kk.ku21, (uint32_t)k)) * SUBR + 1e-6f);
    float b1 = -0.1f * logf(u1);
    float b2 = -0.1f * logf(u2);
    w1w[k] = 1.0f - expf(-b1);
    w2w[k] = 1.0f - expf(-b2);
    i1w[k] = i1; i2w[k] = i2; pw[k] = p;

    float sb = b1 + b2;
    for (int r = 0; r < 16; r++) sb += b1r[p * 16 + r] + b2r[p * 16 + r];
    float prior = -sb / 0.1f - 34.0f * logf(0.1f);

    float topo_sum = 0.0f; int cnt = 0;
    for (int t = 0; t < 15; t++) {
      int lct;
      if (t == i1)      lct = lc[p * 16 + i1] + lc[p * 16 + i2];
      else if (t == i2) lct = lc[p * 16 + 15];
      else              lct = lc[p * 16 + t];
      int ti = 2 * lct - 3; ti = ti < 0 ? 0 : (ti > 63 ? 63 : ti);
      if (lct >= 2) topo_sum -= ldf[ti];
      if (lct > 1) cnt++;
    }
    float log_v_minus = logf(fmaxf((float)cnt, 1.0f));
    float log_v_plus = logf(120.0f);
    cw[k] = prior + topo_sum - logpi[p] + log_v_minus - log_v_plus;
  }
  __syncthreads();

  if (tid < 4) {
    int a = tid, i1 = sh_i1, i2 = sh_i2, p2 = sidx[0];
    const float* e1 = emb + ((size_t)p2 * 16 + i1) * 64;
    const float* e2 = emb + ((size_t)p2 * 16 + i2) * 64;
    float acc = 0.0f;
    for (int d = 0; d < 64; d++) acc += 0.5f * (e1[d] + e2[d]) * Wstat[d * 4 + a];
    enlm[k * 4 + a] = __expf(acc);
  }
}

// ---------------------------------------------------------------------------
// Kernel C: Lorig partials, only for used particles. Grid (4 sblk, 256 p).
// Accumulates in log2 domain; scales by ln2 once at the end.
// ---------------------------------------------------------------------------
__global__ __launch_bounds__(256) void k_lorig(
    const float* __restrict__ lfg, const float* __restrict__ eslw,
    const float* __restrict__ emb, const float* __restrict__ Wstat,
    const int* __restrict__ used, float* __restrict__ Lpart) {
  int p = blockIdx.y, sblk = blockIdx.x, tid = threadIdx.x;
  if (used[p] == 0) return;
  __shared__ float enl[64];
  __shared__ float sred[16 * 4];
  if (tid < 64) {
    int t = tid >> 2, a = tid & 3;
    const float4* e4 = (const float4*)(emb + ((size_t)p * 16 + t) * 64);
    float acc = 0.0f;
#pragma unroll
    for (int d4 = 0; d4 < 16; d4++) {
      float4 e = e4[d4];
      acc += e.x * Wstat[(d4 * 4 + 0) * 4 + a] + e.y * Wstat[(d4 * 4 + 1) * 4 + a] +
             e.z * Wstat[(d4 * 4 + 2) * 4 + a] + e.w * Wstat[(d4 * 4 + 3) * 4 + a];
    }
    enl[tid] = __expf(acc);
  }
  __syncthreads();
  int s = sblk * 256 + tid;
  const float4 esl = ((const float4*)eslw)[s];
  const float* base = lfg + (size_t)p * 65536;

  float acc[16];
#pragma unroll
  for (int t = 0; t < 16; t++) {
    float4 lf = *(const float4*)(base + t * 4096 + s * 4);
    float w0 = enl[t * 4 + 0] * esl.x, w1 = enl[t * 4 + 1] * esl.y;
    float w2 = enl[t * 4 + 2] * esl.z, w3 = enl[t * 4 + 3] * esl.w;
    float S1 = w0 + w1 + w2 + w3;
    float S2 = __expf(lf.x) * w0 + __expf(lf.y) * w1 +
               __expf(lf.z) * w2 + __expf(lf.w) * w3;
    acc[t] = __log2f(S2) - __log2f(S1);
  }
#pragma unroll
  for (int t = 0; t < 16; t++) {
    float v = acc[t];
    for (int o = 32; o > 0; o >>= 1) v += __shfl_down(v, o, 64);
    if ((tid & 63) == 0) sred[t * 4 + (tid >> 6)] = v;
  }
  __syncthreads();
  if (tid < 16) {
    float s4 = sred[tid * 4 + 0] + sred[tid * 4 + 1] + sred[tid * 4 + 2] + sred[tid * 4 + 3];
    Lpart[((size_t)p * 4 + sblk) * 16 + tid] = s4 * 0.69314718056f;  // ln2
  }
}

// ---------------------------------------------------------------------------
// Kernel D: merged-node term over sites + final combine. 256 blocks (k) x 1024.
// ---------------------------------------------------------------------------
__global__ __launch_bounds__(1024) void k_fin(
    const float* __restrict__ lfg, const float* __restrict__ eslw,
    const float* __restrict__ enlm, const float* __restrict__ w1w,
    const float* __restrict__ w2w, const int* __restrict__ pw,
    const int* __restrict__ i1w, const int* __restrict__ i2w,
    const float* __restrict__ cw, const float* __restrict__ Lpart,
    float* __restrict__ out) {
  int k = blockIdx.x, tid = threadIdx.x;
  __shared__ float sred[16];
  int p = pw[k], i1 = i1w[k], i2 = i2w[k];
  float w1 = w1w[k], w2 = w2w[k];
  float om1 = 1.0f - w1, om2 = 1.0f - w2;
  float m0 = enlm[k * 4 + 0], m1 = enlm[k * 4 + 1];
  float m2 = enlm[k * 4 + 2], m3 = enlm[k * 4 + 3];
  const float* base = lfg + (size_t)p * 65536;

  int s = tid;
  const float4 esl = ((const float4*)eslw)[s];
  float t0 = m0 * esl.x, t1 = m1 * esl.y, t2 = m2 * esl.z, t3 = m3 * esl.w;
  float T = t0 + t1 + t2 + t3;
  float invT = 1.0f / T;
  float4 lf1 = *(const float4*)(base + i1 * 4096 + s * 4);
  float4 lf2 = *(const float4*)(base + i2 * 4096 + s * 4);
  float f10 = __expf(lf1.x), f11 = __expf(lf1.y), f12 = __expf(lf1.z), f13 = __expf(lf1.w);
  float f20 = __expf(lf2.x), f21 = __expf(lf2.y), f22 = __expf(lf2.z), f23 = __expf(lf2.w);
  float dot1 = (t0 * f10 + t1 * f11 + t2 * f12 + t3 * f13) * invT;
  float dot2 = (t0 * f20 + t1 * f21 + t2 * f22 + t3 * f23) * invT;
  float n0 = __logf(om1 * f10 + w1 * dot1 + 1e-30f) + __logf(om2 * f20 + w2 * dot2 + 1e-30f);
  float n1 = __logf(om1 * f11 + w1 * dot1 + 1e-30f) + __logf(om2 * f21 + w2 * dot2 + 1e-30f);
  float n2 = __logf(om1 * f12 + w1 * dot1 + 1e-30f) + __logf(om2 * f22 + w2 * dot2 + 1e-30f);
  float n3 = __logf(om1 * f13 + w1 * dot1 + 1e-30f) + __logf(om2 * f23 + w2 * dot2 + 1e-30f);
  float S2 = __expf(n0) * t0 + __expf(n1) * t1 + __expf(n2) * t2 + __expf(n3) * t3;
  float tot = __logf(S2) - __logf(T);

  for (int o = 32; o > 0; o >>= 1) tot += __shfl_down(tot, o, 64);
  if ((tid & 63) == 0) sred[tid >> 6] = tot;
  __syncthreads();
  if (tid < 64) {
    // Lpart layout [p][sblk(4)][t(16)]: slot t = tid & 15.
    int t = tid & 15;
    float coef = (t == i1 || t == i2) ? 0.0f : 1.0f;
    float v = coef * Lpart[(size_t)p * 64 + tid];
    if (tid < 16) v += sred[tid];
    for (int o = 32; o > 0; o >>= 1) v += __shfl_down(v, o, 64);
    if (tid == 0) out[k] = cw[k] + v;
  }
}

// ---------------------------------------------------------------------------
extern "C" void kernel_launch(void* const* d_in, const int* in_sizes, int n_in,
                              void* d_out, int out_size, void* d_ws, size_t ws_size,
                              hipStream_t stream) {
  const float* logw  = (const float*)d_in[0];
  const float* b1r   = (const float*)d_in[1];
  const float* b2r   = (const float*)d_in[2];
  const int*   lc    = (const int*)d_in[3];
  const float* emb   = (const float*)d_in[4];
  const float* lfg   = (const float*)d_in[5];
  const float* logpi = (const float*)d_in[6];
  const float* site  = (const float*)d_in[7];
  const float* Wstat = (const float*)d_in[8];
  const float* Wsite = (const float*)d_in[9];
  const float* ldf   = (const float*)d_in[10];

  char* w = (char*)d_ws;
  float* eslw  = (float*)w; w += 1024 * 4 * 4;
  float* enlm  = (float*)w; w += 256 * 4 * 4;
  float* w1w   = (float*)w; w += 256 * 4;
  float* w2w   = (float*)w; w += 256 * 4;
  float* cw    = (float*)w; w += 256 * 4;
  int*   pw    = (int*)w;   w += 256 * 4;
  int*   i1w   = (int*)w;   w += 256 * 4;
  int*   i2w   = (int*)w;   w += 256 * 4;
  int*   used  = (int*)w;   w += 256 * 4;
  float* Lpart = (float*)w; w += 256 * 64 * 4;

  uint32_t S0[5], S1[5];
  for (uint32_t i = 0; i < 5; i++) tf2x32(0u, 42u, 0u, i, S0[i], S1[i]);
  Keys kk;
  kk.kres0 = S0[0]; kk.kres1 = S1[0];
  kk.ku10  = S0[3]; kk.ku11  = S1[3];
  kk.ku20  = S0[4]; kk.ku21  = S1[4];
  {
    uint32_t a0, a1, b0, b1;
    tf2x32(S0[1], S1[1], 0u, 0u, a0, a1);
    tf2x32(S0[1], S1[1], 0u, 1u, b0, b1);
    (void)a0; (void)a1;
    kk.k2i0 = b0; kk.k2i1 = b1;
  }
  {
    uint32_t a0, a1, b0, b1;
    tf2x32(S0[2], S1[2], 0u, 0u, a0, a1);
    tf2x32(S0[2], S1[2], 0u, 1u, b0, b1);
    kk.k1o0 = a0; kk.k1o1 = a1;
    kk.k2o0 = b0; kk.k2o1 = b1;
  }

  k_pre<<<4, 256, 0, stream>>>(site, Wsite, eslw, used);
  k_setup<<<256, 256, 0, stream>>>(logw, b1r, b2r, lc, emb, logpi, Wstat, ldf,
                                   enlm, w1w, w2w, cw, pw, i1w, i2w, used, kk);
  dim3 gC(4, 256);
  k_lorig<<<gC, 256, 0, stream>>>(lfg, eslw, emb, Wstat, used, Lpart);
  k_fin<<<256, 1024, 0, stream>>>(lfg, eslw, enlm, w1w, w2w, pw, i1w, i2w,
                                  cw, Lpart, (float*)d_out);
}